// Round 9
// baseline (251.793 us; speedup 1.0000x reference)
//
#include <hip/hip_runtime.h>
#include <hip/hip_bf16.h>

// GAT on MI355X. Inputs fp32 (+ int32 adj); OUTPUT IS FLOAT32 (established R8:
// d_out is fp32 — bf16 writes land in low halves and read back as denormals).
// Layout: d_out[0..8) = out, d_out[8..32776) = node_embeddings (return order).
//  kAs: Wh[h][n][8] fp32 = x @ W_h  (LDS-tiled fp32 GEMM)
//  kB : s_src/s_dst = Wh . a1/a2
//  kC : mhat[h] = max_n s_dst[h][n]   (upper bound for softmax shift)
//  kD : fused masked-softmax attention + aggregation + head-mean -> d_out+8
//  kE : per-row log_softmax + w_lin partial sums (32 block partials)
//  kF : out[8] = sum partials + b_lin -> d_out[0..8)

typedef __attribute__((ext_vector_type(4))) float f32x4;
typedef __attribute__((ext_vector_type(2))) float f32x2;

#define NN 4096
#define NC 8

__device__ __forceinline__ bool is_adj(const void* p) {
  const unsigned* u = (const unsigned*)p;
  // adj dwords are 0 or 1; fp32 N(0,1) bit patterns are never <= 1
  unsigned m = u[0] | u[1] | u[2] | u[3] | u[100] | u[1000];
  return m <= 1u;
}

// ---------- kAs: tiled fp32 GEMM. 256 blocks x 256 thr; block = 16 rows x 32 cols ----------
__global__ __launch_bounds__(256) void kAs(const void* __restrict__ c0, const void* __restrict__ c1,
                                           const float* __restrict__ W, float* __restrict__ Wh) {
  const float* x = (const float*)(is_adj(c0) ? c1 : c0);
  __shared__ float xc[16][260];   // +4 pad
  __shared__ float wc[256][32];   // inner read is loop-uniform k -> broadcast
  int t = threadIdx.x;
  int n0 = blockIdx.x * 16;
  int r = t >> 4, co = (t & 15) * 2;
  float acc0 = 0.f, acc1 = 0.f;
  for (int k0 = 0; k0 < NN; k0 += 256) {
    __syncthreads();
    {  // stage x tile: 16 rows x 256 k
      int rr = t >> 4, kb = (t & 15) * 16;
      const f32x4* gp = (const f32x4*)(x + (size_t)(n0 + rr) * NN + k0 + kb);
#pragma unroll
      for (int i = 0; i < 4; ++i) *(f32x4*)&xc[rr][kb + 4 * i] = gp[i];
    }
#pragma unroll
    for (int j = 0; j < 8; ++j) {  // stage W tile: wc[k][h*8+o] = W[h][k0+k][o]
      int flat = (t + 256 * j) * 4;                            // [0, 8192) step 4
      int h = flat >> 11, k = (flat >> 3) & 255, o = flat & 7; // o in {0,4}
      f32x4 v = *(const f32x4*)(W + (size_t)h * (NN * NC) + (size_t)(k0 + k) * NC + o);
      *(f32x4*)&wc[k][h * 8 + o] = v;
    }
    __syncthreads();
#pragma unroll 8
    for (int k = 0; k < 256; ++k) {
      float xv = xc[r][k];
      f32x2 wv = *(const f32x2*)&wc[k][co];
      acc0 += xv * wv[0];
      acc1 += xv * wv[1];
    }
  }
  int n = n0 + r;
  int h = co >> 3, o = co & 7;
  Wh[((size_t)h * NN + n) * NC + o] = acc0;
  int c2 = co + 1, h2 = c2 >> 3, o2 = c2 & 7;
  Wh[((size_t)h2 * NN + n) * NC + o2] = acc1;
}

// ---------- kB: s_src/s_dst = Wh . a1/a2 ----------
__global__ __launch_bounds__(256) void kB(const float* __restrict__ Wh, const float* __restrict__ a,
                                          float* __restrict__ ssrc, float* __restrict__ sdst) {
  int g = blockIdx.x * 256 + threadIdx.x;   // 16384; g = h*4096 + n
  int h = g >> 12;
  f32x4 v0 = *(const f32x4*)(Wh + (size_t)g * 8);
  f32x4 v1 = *(const f32x4*)(Wh + (size_t)g * 8 + 4);
  float s1 = 0.f, s2 = 0.f;
#pragma unroll
  for (int e = 0; e < 4; ++e) {
    s1 += v0[e] * a[h * 16 + e]     + v1[e] * a[h * 16 + 4 + e];
    s2 += v0[e] * a[h * 16 + 8 + e] + v1[e] * a[h * 16 + 12 + e];
  }
  ssrc[g] = s1;
  sdst[g] = s2;
}

// ---------- kC: per-head global max of s_dst ----------
__global__ __launch_bounds__(256) void kC(const float* __restrict__ sdst, float* __restrict__ mhat) {
  int h = blockIdx.x, t = threadIdx.x;
  float m = -1e30f;
  for (int n = t; n < NN; n += 256) m = fmaxf(m, sdst[h * NN + n]);
  for (int mm = 1; mm <= 32; mm <<= 1) m = fmaxf(m, __shfl_xor(m, mm));
  __shared__ float sm[4];
  if ((t & 63) == 0) sm[t >> 6] = m;
  __syncthreads();
  if (t == 0) mhat[h] = fmaxf(fmaxf(sm[0], sm[1]), fmaxf(sm[2], sm[3]));
}

// ---------- kD: fused attention + aggregation + head-mean -> fp32 node_emb ----------
// 512 blocks x 256 thr. Block: 8 rows. Wave = head. Lane: ig=lane>>4 -> rows 2ig,2ig+1;
// sub=lane&15 -> j stripe. Shift eb = lrelu(ssrc + mhat) >= any masked e -> exp<=1;
// ratios match literal softmax exactly.
__global__ __launch_bounds__(256) void kD(const void* __restrict__ c0, const void* __restrict__ c1,
                                          const float* __restrict__ Wh,
                                          const float* __restrict__ ssrcg, const float* __restrict__ sdstg,
                                          const float* __restrict__ mhat,
                                          float* __restrict__ neF) {
  const int* adj = (const int*)(is_adj(c0) ? c0 : c1);
  __shared__ float whc[4][256][12];
  __shared__ int   adjt[8][257];
  __shared__ float sdl[4][256];
  __shared__ float red2[4][8][8];
  int t = threadIdx.x;
  int h = t >> 6, lane = t & 63;
  int sub = lane & 15, ig = lane >> 4;
  int i0 = blockIdx.x * 8;

  float mh = mhat[h];
  float ssr0 = ssrcg[h * NN + i0 + 2 * ig + 0];
  float ssr1 = ssrcg[h * NN + i0 + 2 * ig + 1];
  float tb0 = ssr0 + mh, tb1 = ssr1 + mh;
  float eb0 = fmaxf(tb0, 0.2f * tb0);
  float eb1 = fmaxf(tb1, 0.2f * tb1);
  float l0 = 0.f, l1 = 0.f;
  f32x4 a00 = {0,0,0,0}, a01 = {0,0,0,0}, a10 = {0,0,0,0}, a11 = {0,0,0,0};

  for (int jc = 0; jc < NN; jc += 256) {
    __syncthreads();
#pragma unroll
    for (int r = 0; r < 8; ++r)
      adjt[r][t] = adj[(size_t)(i0 + r) * NN + jc + t];
#pragma unroll
    for (int rep = 0; rep < 8; ++rep) {          // 8192 floats of Wh chunk
      int idx = rep * 1024 + t * 4;
      int hh = idx >> 11, r1 = idx & 2047, jl = r1 >> 3, o0 = r1 & 7;
      f32x4 v = *(const f32x4*)(Wh + (size_t)hh * (NN * NC) + (size_t)(jc + jl) * NC + o0);
      *(f32x4*)&whc[hh][jl][o0] = v;
    }
    {
      int hh = t >> 6, jl = (t & 63) * 4;
      *(f32x4*)&sdl[hh][jl] = *(const f32x4*)(sdstg + (size_t)hh * NN + jc + jl);
    }
    __syncthreads();
#pragma unroll 2
    for (int jj = 0; jj < 16; ++jj) {
      int j = sub + jj * 16;
      float sd = sdl[h][j];
      f32x4 wv0 = *(const f32x4*)&whc[h][j][0];
      f32x4 wv1 = *(const f32x4*)&whc[h][j][4];
      int av0 = adjt[2 * ig + 0][j];
      int av1 = adjt[2 * ig + 1][j];
      float t0 = ssr0 + sd, t1 = ssr1 + sd;
      float e0 = fmaxf(t0, 0.2f * t0);
      float e1 = fmaxf(t1, 0.2f * t1);
      float w0 = __expf(e0 - eb0);
      float w1 = __expf(e1 - eb1);
      w0 = (av0 > 0) ? w0 : 0.f;
      w1 = (av1 > 0) ? w1 : 0.f;
      l0 += w0; l1 += w1;
      a00 += w0 * wv0; a01 += w0 * wv1;
      a10 += w1 * wv0; a11 += w1 * wv1;
    }
  }
#pragma unroll
  for (int m = 1; m <= 8; m <<= 1) {
    l0 += __shfl_xor(l0, m);
    l1 += __shfl_xor(l1, m);
#pragma unroll
    for (int e = 0; e < 4; ++e) {
      a00[e] += __shfl_xor(a00[e], m);
      a01[e] += __shfl_xor(a01[e], m);
      a10[e] += __shfl_xor(a10[e], m);
      a11[e] += __shfl_xor(a11[e], m);
    }
  }
  if (sub == 0) {
    float i0v = 1.f / l0, i1v = 1.f / l1;
#pragma unroll
    for (int e = 0; e < 4; ++e) {
      red2[h][2 * ig + 0][e]     = a00[e] * i0v;
      red2[h][2 * ig + 0][4 + e] = a01[e] * i0v;
      red2[h][2 * ig + 1][e]     = a10[e] * i1v;
      red2[h][2 * ig + 1][4 + e] = a11[e] * i1v;
    }
  }
  __syncthreads();
  if (t < 64) {
    int i = t >> 3, o = t & 7;
    float ne = 0.25f * (red2[0][i][o] + red2[1][i][o] + red2[2][i][o] + red2[3][i][o]);
    neF[(size_t)(i0 + i) * NC + o] = ne;    // fp32 store straight into d_out+8
  }
}

// ---------- kE: log_softmax rows (fp32 node_emb from d_out) + w_lin partial sums ----------
__global__ __launch_bounds__(128) void kE(const float* __restrict__ neF, const float* __restrict__ wlin,
                                          float* __restrict__ partials) {
  int t = threadIdx.x;
  int n = blockIdx.x * 128 + t;
  f32x4 v0 = *(const f32x4*)(neF + (size_t)n * NC);
  f32x4 v1 = *(const f32x4*)(neF + (size_t)n * NC + 4);
  float m = v0[0];
#pragma unroll
  for (int e = 1; e < 4; ++e) m = fmaxf(m, v0[e]);
#pragma unroll
  for (int e = 0; e < 4; ++e) m = fmaxf(m, v1[e]);
  float s = 0.f;
#pragma unroll
  for (int e = 0; e < 4; ++e) s += __expf(v0[e] - m);
#pragma unroll
  for (int e = 0; e < 4; ++e) s += __expf(v1[e] - m);
  float ln = m + __logf(s);
  float wl = wlin[n];
  float p[8];
#pragma unroll
  for (int e = 0; e < 4; ++e) p[e] = (v0[e] - ln) * wl;
#pragma unroll
  for (int e = 0; e < 4; ++e) p[4 + e] = (v1[e] - ln) * wl;
#pragma unroll
  for (int mm = 1; mm <= 32; mm <<= 1)
#pragma unroll
    for (int o = 0; o < 8; ++o) p[o] += __shfl_xor(p[o], mm);
  __shared__ float wsum[2][8];
  if ((t & 63) == 0)
#pragma unroll
    for (int o = 0; o < 8; ++o) wsum[t >> 6][o] = p[o];
  __syncthreads();
  if (t < 8) partials[blockIdx.x * 8 + t] = wsum[0][t] + wsum[1][t];
}

// ---------- kF: final out[8] (fp32) ----------
__global__ __launch_bounds__(64) void kF(const float* __restrict__ partials, const float* __restrict__ blin,
                                         float* __restrict__ out) {
  int t = threadIdx.x;
  if (t < 8) {
    float s = blin[0];
    for (int b = 0; b < 32; ++b) s += partials[b * 8 + t];
    out[t] = s;
  }
}

extern "C" void kernel_launch(void* const* d_in, const int* in_sizes, int n_in,
                              void* d_out, int out_size, void* d_ws, size_t ws_size,
                              hipStream_t stream) {
  // Identify inputs by element count (robust to ordering); x/adj disambiguated on-device.
  const void* big0 = nullptr; const void* big1 = nullptr;
  const float* W = nullptr; const float* a = nullptr;
  const float* wlin = nullptr; const float* blin = nullptr;
  for (int idx = 0; idx < n_in; ++idx) {
    int sz = in_sizes[idx];
    if (sz == NN * NN)          { if (!big0) big0 = d_in[idx]; else big1 = d_in[idx]; }
    else if (sz == 4 * NN * NC) W    = (const float*)d_in[idx];
    else if (sz == 64)          a    = (const float*)d_in[idx];
    else if (sz == NN)          wlin = (const float*)d_in[idx];
    else if (sz == 1)           blin = (const float*)d_in[idx];
  }
  float* outF = (float*)d_out;       // fp32: [8] out | [4096][8] node_embeddings
  float* neF  = outF + 8;

  char* ws = (char*)d_ws;                 // 656,640 B total
  float* Wh      = (float*)(ws + 0);      // 524288 B
  float* ssrc    = (float*)(ws + 524288); // 65536 B
  float* sdst    = (float*)(ws + 589824); // 65536 B
  float* mhat    = (float*)(ws + 655360); // 256 B
  float* partials= (float*)(ws + 655616); // 1024 B

  kAs<<<256, 256, 0, stream>>>(big0, big1, W, Wh);
  kB <<<64,  256, 0, stream>>>(Wh, a, ssrc, sdst);
  kC <<<4,   256, 0, stream>>>(sdst, mhat);
  kD <<<512, 256, 0, stream>>>(big0, big1, Wh, ssrc, sdst, mhat, neF);
  kE <<<32,  128, 0, stream>>>(neF, wlin, partials);
  kF <<<1,   64,  0, stream>>>(partials, blin, outF);
}

// Round 10
// 203.559 us; speedup vs baseline: 1.2370x; 1.2370x over previous
//
#include <hip/hip_runtime.h>
#include <hip/hip_bf16.h>

// GAT on MI355X. Inputs fp32 (+ int32 adj); output fp32 [8 | 4096*8].
//  kA0: W[4][4096][8] fp32 -> Wt[32][4096] bf16 (transposed, B-operand layout)
//  kA : Wh[h][n][8] fp32 = x @ W_h via MFMA bf16 (x converted in-flight);
//       epilogue: s_src/s_dst = Wh . a1/a2  (kB fused away)
//  kC : mhat[h] = max_n s_dst[h][n]   (upper bound for softmax shift)
//  kD : fused masked-softmax attention + aggregation + head-mean -> d_out+8
//  kE : per-row log_softmax + w_lin partial sums
//  kF : out[8] = sum partials + b_lin -> d_out[0..8)

typedef __attribute__((ext_vector_type(8))) short bf16x8;   // MFMA A/B frag (4 VGPRs)
typedef __attribute__((ext_vector_type(4))) float f32x4;

#define NN 4096
#define NC 8

__device__ __forceinline__ short f2bf(float f) {
  __hip_bfloat16 h = __float2bfloat16(f);
  return *reinterpret_cast<short*>(&h);
}

__device__ __forceinline__ bool is_adj(const void* p) {
  const unsigned* u = (const unsigned*)p;
  unsigned m = u[0] | u[1] | u[2] | u[3] | u[100] | u[1000];
  return m <= 1u;   // adj dwords are 0/1; fp32 N(0,1) bits never <= 1
}

// ---------- kA0: W[h][f][o] fp32 -> Wt[h*8+o][f] bf16 ----------
__global__ __launch_bounds__(256) void kA0(const float* __restrict__ W, short* __restrict__ Wt) {
  int idx = blockIdx.x * 256 + threadIdx.x;      // 131072
  int h = idx >> 15, r = idx & 32767, f = r >> 3, o = r & 7;
  Wt[(size_t)(h * 8 + o) * NN + f] = f2bf(W[idx]);
}

// ---------- kA: Wh = x @ W via MFMA 16x16x32 bf16, + scores ----------
// 256 blocks x 256 thr (4 waves). Block: 16 rows x 32 cols; wave w: k in [w*1024, (w+1)*1024).
// A-frag: A[m=lane&15][k=q*8+j]; B-frag: B[k=q*8+j][n=lane&15] (from Wt rows).
// D: n=lane&15, m=q*4+reg  [m89/m91-verified layout].
__global__ __launch_bounds__(256) void kA(const void* __restrict__ c0, const void* __restrict__ c1,
                                          const short* __restrict__ Wt,
                                          float* __restrict__ Wh, float* __restrict__ ssrc,
                                          float* __restrict__ sdst, const float* __restrict__ a) {
  const float* x = (const float*)(is_adj(c0) ? c1 : c0);
  int m0 = blockIdx.x * 16;
  int t = threadIdx.x;
  int w = t >> 6, lane = t & 63;
  int mr = lane & 15, q = lane >> 4;
  const f32x4*  ap  = (const f32x4*)(x + (size_t)(m0 + mr) * NN + w * 1024 + q * 8);
  const bf16x8* b0p = (const bf16x8*)(Wt + (size_t)mr        * NN + w * 1024 + q * 8);
  const bf16x8* b1p = (const bf16x8*)(Wt + (size_t)(16 + mr) * NN + w * 1024 + q * 8);
  f32x4 acc0 = {0.f, 0.f, 0.f, 0.f}, acc1 = {0.f, 0.f, 0.f, 0.f};
#pragma unroll 4
  for (int kk = 0; kk < 32; ++kk) {      // 32 k-steps of 32
    f32x4 xa = ap[kk * 8];
    f32x4 xb = ap[kk * 8 + 1];
    bf16x8 af;
#pragma unroll
    for (int e = 0; e < 4; ++e) { af[e] = f2bf(xa[e]); af[4 + e] = f2bf(xb[e]); }
    bf16x8 b0 = b0p[kk * 4];
    bf16x8 b1 = b1p[kk * 4];
    acc0 = __builtin_amdgcn_mfma_f32_16x16x32_bf16(af, b0, acc0, 0, 0, 0);
    acc1 = __builtin_amdgcn_mfma_f32_16x16x32_bf16(af, b1, acc1, 0, 0, 0);
  }
  __shared__ float red[4][16][32];
  __shared__ float whole[16][32];
#pragma unroll
  for (int r = 0; r < 4; ++r) {
    red[w][q * 4 + r][mr]      = acc0[r];
    red[w][q * 4 + r][16 + mr] = acc1[r];
  }
  __syncthreads();
  for (int idx = t; idx < 512; idx += 256) {
    int m = idx >> 5, c = idx & 31;
    float s = red[0][m][c] + red[1][m][c] + red[2][m][c] + red[3][m][c];
    whole[m][c] = s;
    int h = c >> 3, o = c & 7;
    Wh[((size_t)h * NN + m0 + m) * NC + o] = s;
  }
  __syncthreads();
  if (t < 64) {
    int h = t >> 4, m = t & 15;
    float s1 = 0.f, s2 = 0.f;
#pragma unroll
    for (int o = 0; o < 8; ++o) {
      float v = whole[m][h * 8 + o];
      s1 += v * a[h * 16 + o];
      s2 += v * a[h * 16 + 8 + o];
    }
    ssrc[h * NN + m0 + m] = s1;
    sdst[h * NN + m0 + m] = s2;
  }
}

// ---------- kC: per-head global max of s_dst ----------
__global__ __launch_bounds__(256) void kC(const float* __restrict__ sdst, float* __restrict__ mhat) {
  int h = blockIdx.x, t = threadIdx.x;
  float m = -1e30f;
  for (int n = t; n < NN; n += 256) m = fmaxf(m, sdst[h * NN + n]);
  for (int mm = 1; mm <= 32; mm <<= 1) m = fmaxf(m, __shfl_xor(m, mm));
  __shared__ float sm[4];
  if ((t & 63) == 0) sm[t >> 6] = m;
  __syncthreads();
  if (t == 0) mhat[h] = fmaxf(fmaxf(sm[0], sm[1]), fmaxf(sm[2], sm[3]));
}

// ---------- kD: fused attention + aggregation + head-mean -> fp32 node_emb ----------
__global__ __launch_bounds__(256) void kD(const void* __restrict__ c0, const void* __restrict__ c1,
                                          const float* __restrict__ Wh,
                                          const float* __restrict__ ssrcg, const float* __restrict__ sdstg,
                                          const float* __restrict__ mhat,
                                          float* __restrict__ neF) {
  const int* adj = (const int*)(is_adj(c0) ? c0 : c1);
  __shared__ float whc[4][256][12];
  __shared__ int   adjt[8][257];
  __shared__ float sdl[4][256];
  __shared__ float red2[4][8][8];
  int t = threadIdx.x;
  int h = t >> 6, lane = t & 63;
  int sub = lane & 15, ig = lane >> 4;
  int i0 = blockIdx.x * 8;

  float mh = mhat[h];
  float ssr0 = ssrcg[h * NN + i0 + 2 * ig + 0];
  float ssr1 = ssrcg[h * NN + i0 + 2 * ig + 1];
  float tb0 = ssr0 + mh, tb1 = ssr1 + mh;
  float eb0 = fmaxf(tb0, 0.2f * tb0);
  float eb1 = fmaxf(tb1, 0.2f * tb1);
  float l0 = 0.f, l1 = 0.f;
  f32x4 a00 = {0,0,0,0}, a01 = {0,0,0,0}, a10 = {0,0,0,0}, a11 = {0,0,0,0};

  for (int jc = 0; jc < NN; jc += 256) {
    __syncthreads();
#pragma unroll
    for (int r = 0; r < 8; ++r)
      adjt[r][t] = adj[(size_t)(i0 + r) * NN + jc + t];
#pragma unroll
    for (int rep = 0; rep < 8; ++rep) {
      int idx = rep * 1024 + t * 4;
      int hh = idx >> 11, r1 = idx & 2047, jl = r1 >> 3, o0 = r1 & 7;
      f32x4 v = *(const f32x4*)(Wh + (size_t)hh * (NN * NC) + (size_t)(jc + jl) * NC + o0);
      *(f32x4*)&whc[hh][jl][o0] = v;
    }
    {
      int hh = t >> 6, jl = (t & 63) * 4;
      *(f32x4*)&sdl[hh][jl] = *(const f32x4*)(sdstg + (size_t)hh * NN + jc + jl);
    }
    __syncthreads();
#pragma unroll 2
    for (int jj = 0; jj < 16; ++jj) {
      int j = sub + jj * 16;
      float sd = sdl[h][j];
      f32x4 wv0 = *(const f32x4*)&whc[h][j][0];
      f32x4 wv1 = *(const f32x4*)&whc[h][j][4];
      int av0 = adjt[2 * ig + 0][j];
      int av1 = adjt[2 * ig + 1][j];
      float t0 = ssr0 + sd, t1 = ssr1 + sd;
      float e0 = fmaxf(t0, 0.2f * t0);
      float e1 = fmaxf(t1, 0.2f * t1);
      float w0 = __expf(e0 - eb0);
      float w1 = __expf(e1 - eb1);
      w0 = (av0 > 0) ? w0 : 0.f;
      w1 = (av1 > 0) ? w1 : 0.f;
      l0 += w0; l1 += w1;
      a00 += w0 * wv0; a01 += w0 * wv1;
      a10 += w1 * wv0; a11 += w1 * wv1;
    }
  }
#pragma unroll
  for (int m = 1; m <= 8; m <<= 1) {
    l0 += __shfl_xor(l0, m);
    l1 += __shfl_xor(l1, m);
#pragma unroll
    for (int e = 0; e < 4; ++e) {
      a00[e] += __shfl_xor(a00[e], m);
      a01[e] += __shfl_xor(a01[e], m);
      a10[e] += __shfl_xor(a10[e], m);
      a11[e] += __shfl_xor(a11[e], m);
    }
  }
  if (sub == 0) {
    float i0v = 1.f / l0, i1v = 1.f / l1;
#pragma unroll
    for (int e = 0; e < 4; ++e) {
      red2[h][2 * ig + 0][e]     = a00[e] * i0v;
      red2[h][2 * ig + 0][4 + e] = a01[e] * i0v;
      red2[h][2 * ig + 1][e]     = a10[e] * i1v;
      red2[h][2 * ig + 1][4 + e] = a11[e] * i1v;
    }
  }
  __syncthreads();
  if (t < 64) {
    int i = t >> 3, o = t & 7;
    float ne = 0.25f * (red2[0][i][o] + red2[1][i][o] + red2[2][i][o] + red2[3][i][o]);
    neF[(size_t)(i0 + i) * NC + o] = ne;
  }
}

// ---------- kE: log_softmax rows + w_lin partial sums ----------
__global__ __launch_bounds__(128) void kE(const float* __restrict__ neF, const float* __restrict__ wlin,
                                          float* __restrict__ partials) {
  int t = threadIdx.x;
  int n = blockIdx.x * 128 + t;
  f32x4 v0 = *(const f32x4*)(neF + (size_t)n * NC);
  f32x4 v1 = *(const f32x4*)(neF + (size_t)n * NC + 4);
  float m = v0[0];
#pragma unroll
  for (int e = 1; e < 4; ++e) m = fmaxf(m, v0[e]);
#pragma unroll
  for (int e = 0; e < 4; ++e) m = fmaxf(m, v1[e]);
  float s = 0.f;
#pragma unroll
  for (int e = 0; e < 4; ++e) s += __expf(v0[e] - m);
#pragma unroll
  for (int e = 0; e < 4; ++e) s += __expf(v1[e] - m);
  float ln = m + __logf(s);
  float wl = wlin[n];
  float p[8];
#pragma unroll
  for (int e = 0; e < 4; ++e) p[e] = (v0[e] - ln) * wl;
#pragma unroll
  for (int e = 0; e < 4; ++e) p[4 + e] = (v1[e] - ln) * wl;
#pragma unroll
  for (int mm = 1; mm <= 32; mm <<= 1)
#pragma unroll
    for (int o = 0; o < 8; ++o) p[o] += __shfl_xor(p[o], mm);
  __shared__ float wsum[2][8];
  if ((t & 63) == 0)
#pragma unroll
    for (int o = 0; o < 8; ++o) wsum[t >> 6][o] = p[o];
  __syncthreads();
  if (t < 8) partials[blockIdx.x * 8 + t] = wsum[0][t] + wsum[1][t];
}

// ---------- kF: final out[8] ----------
__global__ __launch_bounds__(64) void kF(const float* __restrict__ partials, const float* __restrict__ blin,
                                         float* __restrict__ out) {
  int t = threadIdx.x;
  if (t < 8) {
    float s = blin[0];
    for (int b = 0; b < 32; ++b) s += partials[b * 8 + t];
    out[t] = s;
  }
}

extern "C" void kernel_launch(void* const* d_in, const int* in_sizes, int n_in,
                              void* d_out, int out_size, void* d_ws, size_t ws_size,
                              hipStream_t stream) {
  const void* big0 = nullptr; const void* big1 = nullptr;
  const float* W = nullptr; const float* a = nullptr;
  const float* wlin = nullptr; const float* blin = nullptr;
  for (int idx = 0; idx < n_in; ++idx) {
    int sz = in_sizes[idx];
    if (sz == NN * NN)          { if (!big0) big0 = d_in[idx]; else big1 = d_in[idx]; }
    else if (sz == 4 * NN * NC) W    = (const float*)d_in[idx];
    else if (sz == 64)          a    = (const float*)d_in[idx];
    else if (sz == NN)          wlin = (const float*)d_in[idx];
    else if (sz == 1)           blin = (const float*)d_in[idx];
  }
  float* outF = (float*)d_out;       // fp32: [8] out | [4096][8] node_embeddings
  float* neF  = outF + 8;

  char* ws = (char*)d_ws;                 // 918,784 B total
  short* Wt      = (short*)(ws + 0);      // 262144 B
  float* Wh      = (float*)(ws + 262144); // 524288 B
  float* ssrc    = (float*)(ws + 786432); // 65536 B
  float* sdst    = (float*)(ws + 851968); // 65536 B
  float* mhat    = (float*)(ws + 917504); // 256 B
  float* partials= (float*)(ws + 917760); // 1024 B

  kA0<<<512, 256, 0, stream>>>(W, Wt);
  kA <<<256, 256, 0, stream>>>(big0, big1, Wt, Wh, ssrc, sdst, a);
  kC <<<4,   256, 0, stream>>>(sdst, mhat);
  kD <<<512, 256, 0, stream>>>(big0, big1, Wh, ssrc, sdst, mhat, neF);
  kE <<<32,  128, 0, stream>>>(neF, wlin, partials);
  kF <<<1,   64,  0, stream>>>(partials, blin, outF);
}